// Round 1
// baseline (265.476 us; speedup 1.0000x reference)
//
#include <hip/hip_runtime.h>
#include <hip/hip_bf16.h>

#define HW      262144   // 512*512 spatial positions
#define NCH     128      // channels (GEMM K)
#define NCLS    128      // classes  (GEMM N)
#define KROWS   131072   // gathered rows
#define BM      64       // positions per tile
#define LDK     136      // padded k-pitch in ushorts (272 B = 17*16 B, keeps b128 aligned)

typedef short  bf16x8 __attribute__((ext_vector_type(8)));
typedef float  f32x4  __attribute__((ext_vector_type(4)));

__device__ inline ushort f2bf(float f) {
    union { float f; unsigned u; } v; v.f = f;
    unsigned u = v.u;
    // round-to-nearest-even to bf16
    unsigned r = (u + 0x7FFFu + ((u >> 16) & 1u)) >> 16;
    return (ushort)r;
}

__device__ inline float bf2f(ushort b) {
    union { unsigned u; float f; } v; v.u = ((unsigned)b) << 16;
    return v.f;
}

// Kernel 1: dense GEMM  pred_all[p][n] = sum_c gc[c][p] * W[n][c]   (bf16 logits out, no bias)
// A = gc viewed [K=NCH][M=HW] (k-strided, m-contiguous)  ->  transpose into LDS [m][k]
// B = W_cls [N][K] row-major == B^T layout, k-contiguous -> stage directly [n][k]
__global__ __launch_bounds__(256) void gemm_logits(const float* __restrict__ gc,
                                                   const float* __restrict__ Wc,
                                                   ushort* __restrict__ pred) {
    __shared__ ushort Wl[NCLS * LDK];   // 34816 B
    __shared__ ushort Al[BM   * LDK];   // 17408 B

    const int t    = threadIdx.x;
    const int lane = t & 63;
    const int wv   = t >> 6;     // wave id 0..3
    const int tx   = t & 63;     // position within tile
    const int ty   = t >> 6;     // channel group

    // ---- stage W (once per block): Wl[n][c] = bf16(W[n][c]); coalesced global read
    for (int i = 0; i < 64; ++i) {
        int e = (i << 8) + t;              // 0..16383
        int n = e >> 7, c = e & 127;
        Wl[n * LDK + c] = f2bf(Wc[e]);
    }

    const int l15   = lane & 15;
    const int khalf = (lane >> 4) << 3;    // 0,8,16,24
    const int mrow  = (wv << 4) + l15;     // A-frag row within 64-row tile
    const int rbase = (lane >> 4) << 2;    // C/D row base within 16x16 tile

    for (int tile = 0; tile < 2; ++tile) {
        const int m0 = (blockIdx.x * 2 + tile) * BM;

        __syncthreads();  // W ready (iter 0) / previous tile's MFMA reads of Al done

        // ---- stage A tile with transpose: Al[tx][c], packed ushort2 writes
        #pragma unroll
        for (int cc = 0; cc < 16; ++cc) {
            int c0 = (ty << 5) + (cc << 1);
            float v0 = gc[(size_t)c0 * HW + m0 + tx];
            float v1 = gc[(size_t)(c0 + 1) * HW + m0 + tx];
            ushort2 pk; pk.x = f2bf(v0); pk.y = f2bf(v1);
            *(ushort2*)&Al[tx * LDK + c0] = pk;
        }
        __syncthreads();

        // ---- MFMA: 16 rows per wave x 128 cols, K=128 in 4 steps
        f32x4 acc[8];
        #pragma unroll
        for (int i = 0; i < 8; ++i) acc[i] = (f32x4){0.f, 0.f, 0.f, 0.f};

        #pragma unroll
        for (int kk = 0; kk < 4; ++kk) {
            const int ko = (kk << 5) + khalf;
            bf16x8 a = *(const bf16x8*)&Al[mrow * LDK + ko];
            #pragma unroll
            for (int nt = 0; nt < 8; ++nt) {
                bf16x8 b = *(const bf16x8*)&Wl[((nt << 4) + l15) * LDK + ko];
                acc[nt] = __builtin_amdgcn_mfma_f32_16x16x32_bf16(a, b, acc[nt], 0, 0, 0);
            }
        }

        // ---- store bf16 logits: C/D layout col=lane&15, row=(lane>>4)*4+reg
        #pragma unroll
        for (int nt = 0; nt < 8; ++nt) {
            #pragma unroll
            for (int r = 0; r < 4; ++r) {
                int row = m0 + (wv << 4) + rbase + r;
                int col = (nt << 4) + l15;
                pred[(size_t)row * NCLS + col] = f2bf(acc[nt][r]);
            }
        }
    }
}

// Kernel 2: out[k][n] = softmax_n( bf2f(pred[idx[k]][n]) + bias[n] )
// one wave per row, 2 classes per lane; 8 rows per block (2 per wave)
__global__ __launch_bounds__(256) void gather_softmax(const ushort* __restrict__ pred,
                                                      const int* __restrict__ idx,
                                                      const float* __restrict__ bias,
                                                      float* __restrict__ out) {
    const int t    = threadIdx.x;
    const int lane = t & 63;
    const int wv   = t >> 6;

    const float2 bv = *(const float2*)&bias[lane << 1];
    const int kbase = (blockIdx.x << 3) + (wv << 1);

    #pragma unroll
    for (int r = 0; r < 2; ++r) {
        const int k = kbase + r;
        const int p = idx[k];
        const ushort2 lv = *(const ushort2*)&pred[(size_t)p * NCLS + (lane << 1)];
        float l0 = bf2f(lv.x) + bv.x;
        float l1 = bf2f(lv.y) + bv.y;
        // |logit| < ~4 -> exp safe in fp32 without max subtraction
        float e0 = __expf(l0);
        float e1 = __expf(l1);
        float s = e0 + e1;
        #pragma unroll
        for (int m = 32; m; m >>= 1) s += __shfl_xor(s, m, 64);
        float inv = 1.0f / s;
        float2 o; o.x = e0 * inv; o.y = e1 * inv;
        *(float2*)&out[(size_t)k * NCLS + (lane << 1)] = o;
    }
}

extern "C" void kernel_launch(void* const* d_in, const int* in_sizes, int n_in,
                              void* d_out, int out_size, void* d_ws, size_t ws_size,
                              hipStream_t stream) {
    const float* gc   = (const float*)d_in[0];   // [1,128,512,512] fp32
    const int*   idx  = (const int*)d_in[1];     // [1,131072] indices (int32 view)
    const float* Wc   = (const float*)d_in[2];   // [128,128] fp32
    const float* bias = (const float*)d_in[3];   // [128] fp32
    float* out  = (float*)d_out;                 // [131072,128] fp32
    ushort* pred = (ushort*)d_ws;                // [262144,128] bf16 logits = 64 MiB

    gemm_logits<<<dim3(HW / (2 * BM)), dim3(256), 0, stream>>>(gc, Wc, pred);
    gather_softmax<<<dim3(KROWS / 8), dim3(256), 0, stream>>>(pred, idx, bias, out);
}

// Round 2
// 243.358 us; speedup vs baseline: 1.0909x; 1.0909x over previous
//
#include <hip/hip_runtime.h>
#include <hip/hip_bf16.h>
#include <hip/hip_fp16.h>

#define HW      262144   // 512*512 spatial positions
#define NCH     128      // channels (GEMM K)
#define NCLS    128      // classes  (GEMM N)
#define KROWS   131072   // gathered rows
#define BM      64       // positions per tile
#define OLP     144      // Ol pitch in halfs: 288 B/row -> 16B-aligned, banks shift 8/4rows (conflict-free)

typedef short  bf16x8 __attribute__((ext_vector_type(8)));
typedef float  f32x4  __attribute__((ext_vector_type(4)));

__device__ inline ushort f2bf(float f) {
    union { float f; unsigned u; } v; v.f = f;
    unsigned u = v.u;
    unsigned r = (u + 0x7FFFu + ((u >> 16) & 1u)) >> 16;   // RNE
    return (ushort)r;
}

// Kernel 0: convert W fp32 -> bf16, laid out in MFMA B-fragment order:
//   Wf[((nt*4+kk)*64 + lane)*8 + j] = bf16( W[nt*16+(lane&15)][kk*32+(lane>>4)*8+j] )
__global__ __launch_bounds__(256) void wconv(const float* __restrict__ Wc,
                                             ushort* __restrict__ Wf) {
    int e    = blockIdx.x * 256 + threadIdx.x;   // 0..16383
    int j    = e & 7;
    int slot = e >> 3;
    int lane = slot & 63;
    int kk   = (slot >> 6) & 3;
    int nt   = slot >> 8;
    int n = (nt << 4) + (lane & 15);
    int k = (kk << 5) + ((lane >> 4) << 3) + j;
    Wf[e] = f2bf(Wc[n * NCH + k]);
}

// Kernel 1: pred16[p][n] = softmax_n( sum_c gc[c][p]*W[n][c] + b[n] )  stored fp16
__global__ __launch_bounds__(256) void gemm_probs(const float* __restrict__ gc,
                                                  const ushort* __restrict__ Wf,
                                                  const float* __restrict__ bias,
                                                  ushort* __restrict__ pred) {
    __shared__ ushort Wl[NCLS * NCH];   // 32 KiB, fragment-ordered
    __shared__ ushort AO[BM * OLP];     // 18432 B: A-frags (16 KiB) then Ol transpose buffer

    const int t    = threadIdx.x;
    const int lane = t & 63;
    const int wv   = t >> 6;
    const int l15  = lane & 15;

    // ---- stage W: straight 16B-per-lane async copy, 8 iterations
    #pragma unroll
    for (int i = 0; i < 8; ++i) {
        const ushort* g = Wf + (i << 11) + (t << 3);
        ushort*       l = Wl + (i << 11) + (t << 3);
        __builtin_amdgcn_global_load_lds(
            (const __attribute__((address_space(1))) unsigned*)g,
            (__attribute__((address_space(3))) unsigned*)l, 16, 0, 0);
    }

    // ---- per-lane bias for its 8 column slots
    float bcol[8];
    #pragma unroll
    for (int nt = 0; nt < 8; ++nt) bcol[nt] = bias[(nt << 4) + l15];

    for (int tile = 0; tile < 2; ++tile) {
        const int m0 = (blockIdx.x * 2 + tile) * BM;

        __syncthreads();   // W ready (iter0) / prior tile's Ol reads done

        // ---- stage A tile (64 m x 128 c) as A-fragments, float4 loads + packed cvt
        #pragma unroll
        for (int i = 0; i < 4; ++i) {
            int q  = (i << 8) + t;       // 0..1023 chunk id
            int cp = q >> 4;             // channel pair 0..63
            int mq = q & 15;             // m quad 0..15
            int c0 = cp << 1;
            int m  = mq << 2;
            float4 v0 = *(const float4*)&gc[(size_t)c0 * HW + m0 + m];
            float4 v1 = *(const float4*)&gc[(size_t)(c0 + 1) * HW + m0 + m];
            int kk = c0 >> 5;
            int hi = ((c0 >> 3) & 3) << 4;
            int j  = c0 & 7;
            const float* a0 = (const float*)&v0;
            const float* a1 = (const float*)&v1;
            #pragma unroll
            for (int d = 0; d < 4; ++d) {
                int row   = m + d;
                int lslot = (row & 15) + hi;
                int mt    = row >> 4;
                int addr  = ((((mt << 2) + kk) << 6) + lslot) << 3;
                __hip_bfloat162 pk = __float22bfloat162_rn(make_float2(a0[d], a1[d]));
                *(ushort2*)&AO[addr + j] = *(ushort2*)&pk;
            }
        }
        __syncthreads();

        // ---- MFMA: wave wv owns m-subtile mt=wv (16 rows) x 128 cols
        f32x4 acc[8];
        #pragma unroll
        for (int i = 0; i < 8; ++i) acc[i] = (f32x4){0.f, 0.f, 0.f, 0.f};

        #pragma unroll
        for (int kk = 0; kk < 4; ++kk) {
            bf16x8 a = *(const bf16x8*)&AO[((((wv << 2) + kk) << 6) + lane) << 3];
            #pragma unroll
            for (int nt = 0; nt < 8; ++nt) {
                bf16x8 b = *(const bf16x8*)&Wl[((((nt << 2) + kk) << 6) + lane) << 3];
                acc[nt] = __builtin_amdgcn_mfma_f32_16x16x32_bf16(a, b, acc[nt], 0, 0, 0);
            }
        }

        // ---- fused softmax in registers (C/D layout: col=l15+nt*16, row=(lane>>4)*4+rr)
        float pr[8][4];
        #pragma unroll
        for (int rr = 0; rr < 4; ++rr) {
            float ex[8], s = 0.f;
            #pragma unroll
            for (int nt = 0; nt < 8; ++nt) {
                ex[nt] = __expf(acc[nt][rr] + bcol[nt]);
                s += ex[nt];
            }
            s += __shfl_xor(s, 1, 64);
            s += __shfl_xor(s, 2, 64);
            s += __shfl_xor(s, 4, 64);
            s += __shfl_xor(s, 8, 64);
            float inv = 1.0f / s;
            #pragma unroll
            for (int nt = 0; nt < 8; ++nt) pr[nt][rr] = ex[nt] * inv;
        }

        __syncthreads();   // all MFMA reads of AO done -> safe to overwrite as Ol

        // ---- transpose probs through LDS (fp16), then coalesced dwordx4 stores
        const int rowb = (wv << 4) + ((lane >> 4) << 2);
        #pragma unroll
        for (int nt = 0; nt < 8; ++nt)
            #pragma unroll
            for (int rr = 0; rr < 4; ++rr)
                AO[(rowb + rr) * OLP + (nt << 4) + l15] =
                    __half_as_ushort(__float2half_rn(pr[nt][rr]));
        __syncthreads();

        #pragma unroll
        for (int i = 0; i < 4; ++i) {
            int q   = (i << 8) + t;
            int row = q >> 4;
            int ch  = q & 15;
            int4 v = *(const int4*)&AO[row * OLP + (ch << 3)];
            *(int4*)&pred[(size_t)(m0 + row) * NCLS + (ch << 3)] = v;
        }
    }
}

// Kernel 2: pure gather: out[k][:] = fp32( pred16[idx[k]][:] )
__global__ __launch_bounds__(256) void gather_rows(const ushort* __restrict__ pred,
                                                   const int* __restrict__ idx,
                                                   float* __restrict__ out) {
    const int t    = threadIdx.x;
    const int lane = t & 63;
    const int wv   = t >> 6;
    const int kbase = (blockIdx.x << 4) + (wv << 2);

    int p[4];
    #pragma unroll
    for (int r = 0; r < 4; ++r) p[r] = idx[kbase + r];

    #pragma unroll
    for (int r = 0; r < 4; ++r) {
        __half2 h = *(const __half2*)&pred[(size_t)p[r] * NCLS + (lane << 1)];
        float2 f = __half22float2(h);
        *(float2*)&out[(size_t)(kbase + r) * NCLS + (lane << 1)] = f;
    }
}

extern "C" void kernel_launch(void* const* d_in, const int* in_sizes, int n_in,
                              void* d_out, int out_size, void* d_ws, size_t ws_size,
                              hipStream_t stream) {
    const float* gc   = (const float*)d_in[0];   // [1,128,512,512] fp32
    const int*   idx  = (const int*)d_in[1];     // [1,131072] int32
    const float* Wc   = (const float*)d_in[2];   // [128,128] fp32
    const float* bias = (const float*)d_in[3];   // [128] fp32
    float*  out  = (float*)d_out;                // [131072,128] fp32
    ushort* pred = (ushort*)d_ws;                // [262144,128] fp16 probs = 64 MiB

    // Use the head of d_out as scratch for the swizzled bf16 W (32 KiB);
    // gather_rows later overwrites all of d_out, so this is stream-ordered-safe.
    ushort* Wf = (ushort*)d_out;

    wconv<<<dim3(64), dim3(256), 0, stream>>>(Wc, Wf);
    gemm_probs<<<dim3(HW / (2 * BM)), dim3(256), 0, stream>>>(gc, Wf, bias, pred);
    gather_rows<<<dim3(KROWS / 16), dim3(256), 0, stream>>>(pred, idx, out);
}